// Round 1
// baseline (406.037 us; speedup 1.0000x reference)
//
#include <hip/hip_runtime.h>

#define HDIM 1024
#define TDIM 17
#define BDIM 64
#define SDIM 512
#define NROWS (BDIM * SDIM) /* 32768 */

// ---------------------------------------------------------------------------
// Kernel 1: partial GEMM. thread = (row, k-phase). W read at wave-uniform
// addresses (phase is wave-uniform via readfirstlane) -> s_load, SGPR-held W.
// ---------------------------------------------------------------------------
template <int P>
__global__ __launch_bounds__(64 * P) void gemm_partial(
    const float* __restrict__ x, const float* __restrict__ W,
    float* __restrict__ part) {
  const int KPP = HDIM / P;  // k-range per phase
  int tid = threadIdx.x;
  int lane = tid & 63;
  int p = __builtin_amdgcn_readfirstlane(tid >> 6);  // wave id = phase
  int row = blockIdx.x * 64 + lane;
  const float* xp = x + (size_t)row * HDIM + (size_t)p * KPP;
  const float* wp = W + (size_t)p * KPP;
  float acc[TDIM];
#pragma unroll
  for (int t = 0; t < TDIM; ++t) acc[t] = 0.f;
  const int C = KPP / 4;
#pragma unroll 4
  for (int c = 0; c < C; ++c) {
    float4 xv = ((const float4*)xp)[c];
#pragma unroll
    for (int t = 0; t < TDIM; ++t) {
      const float* wr = wp + t * HDIM + c * 4;  // uniform address -> s_load
      float a = acc[t];
      a = fmaf(xv.x, wr[0], a);
      a = fmaf(xv.y, wr[1], a);
      a = fmaf(xv.z, wr[2], a);
      a = fmaf(xv.w, wr[3], a);
      acc[t] = a;
    }
  }
  float* o = part + ((size_t)p * NROWS + row) * TDIM;
#pragma unroll
  for (int t = 0; t < TDIM; ++t) o[t] = acc[t];
}

// ---------------------------------------------------------------------------
// Kernel 2: reduce partials across phases + bias -> feats output region.
// For P==1, part aliases feats_out (in-place bias add) -- elementwise safe.
// ---------------------------------------------------------------------------
template <int P>
__global__ __launch_bounds__(256) void reduce_bias(
    const float* __restrict__ part, const float* __restrict__ b,
    float* __restrict__ feats_out) {
  int e = blockIdx.x * 256 + threadIdx.x;
  if (e >= NROWS * TDIM) return;
  float s = 0.f;
#pragma unroll
  for (int p = 0; p < P; ++p) s += part[(size_t)p * NROWS * TDIM + e];
  feats_out[e] = s + b[e % TDIM];
}

// ---------------------------------------------------------------------------
// Kernel 3: Viterbi forward + backtrace. One 64-thread block per batch.
// Scores replicated across lanes in 17 VGPRs; lane j holds transitions
// column j; backpointers in LDS as bytes; feats staged in LDS once.
// ---------------------------------------------------------------------------
__global__ __launch_bounds__(64) void viterbi_kernel(
    const float* __restrict__ feats, const float* __restrict__ trans,
    const float* __restrict__ start_t, const float* __restrict__ end_t,
    const int* __restrict__ nwords, float* __restrict__ tags_out) {
  __shared__ __align__(16) float s_feats[SDIM * TDIM];
  __shared__ unsigned char s_bp[SDIM * TDIM];
  __shared__ unsigned char s_tags[SDIM];
  int b = blockIdx.x;
  int lane = threadIdx.x;
  const float* fb = feats + (size_t)b * SDIM * TDIM;
  {  // stage feats: 8704 floats = 2176 float4 = 34 per lane, coalesced
    const float4* src = (const float4*)fb;
    float4* dst = (float4*)s_feats;
    for (int i = lane; i < (SDIM * TDIM) / 4; i += 64) dst[i] = src[i];
  }
  __syncthreads();

  int nw = nwords[b];
  if (nw < 1) nw = 1;
  if (nw > SDIM) nw = SDIM;
  int jj = lane < TDIM ? lane : TDIM - 1;

  float tcol[TDIM];  // transitions column jj (lane-private)
#pragma unroll
  for (int i = 0; i < TDIM; ++i) tcol[i] = trans[i * TDIM + jj];

  float s[TDIM];  // scores, replicated in every lane
#pragma unroll
  for (int i = 0; i < TDIM; ++i) s[i] = start_t[i] + s_feats[i];

  float fcur = s_feats[TDIM + jj];  // feats for t=1 (unused if nw==1)

  for (int t = 1; t < nw; ++t) {
    float v[TDIM];
    int ix[TDIM];
#pragma unroll
    for (int i = 0; i < TDIM; ++i) {
      v[i] = s[i] + tcol[i];
      ix[i] = i;
    }
    // first-max argmax tree (strict > keeps lower index, matches jnp.argmax)
#define CMB(a, c)            \
  if (v[c] > v[a]) {         \
    v[a] = v[c];             \
    ix[a] = ix[c];           \
  }
    CMB(0, 1) CMB(2, 3) CMB(4, 5) CMB(6, 7)
    CMB(8, 9) CMB(10, 11) CMB(12, 13) CMB(14, 15)
    CMB(0, 2) CMB(4, 6) CMB(8, 10) CMB(12, 14)
    CMB(0, 4) CMB(8, 12)
    CMB(0, 8)
    CMB(0, 16)
#undef CMB
    int tn = (t + 1 < SDIM) ? (t + 1) : (SDIM - 1);
    float fnext = s_feats[tn * TDIM + jj];
    float ns = v[0] + fcur;
    if (lane < TDIM) s_bp[t * TDIM + lane] = (unsigned char)ix[0];
#pragma unroll
    for (int i = 0; i < TDIM; ++i) s[i] = __shfl(ns, i);
    fcur = fnext;
  }
  __syncthreads();  // bp visible

  // last_tag = argmax(score + end_trans), first-max
  float bv = s[0] + end_t[0];
  int bi = 0;
#pragma unroll
  for (int j = 1; j < TDIM; ++j) {
    float c = s[j] + end_t[j];
    if (c > bv) {
      bv = c;
      bi = j;
    }
  }
  // backtrace (all lanes redundantly, uniform -> LDS broadcast reads)
  int tag = bi;
  s_tags[nw - 1] = (unsigned char)tag;
  for (int t = nw - 1; t >= 1; --t) {
    tag = s_bp[t * TDIM + tag];
    s_tags[t - 1] = (unsigned char)tag;
  }
  __syncthreads();
  float* ob = tags_out + (size_t)b * SDIM;
  for (int t = lane; t < SDIM; t += 64)
    ob[t] = (t < nw) ? (float)s_tags[t] : 0.f;
}

// ---------------------------------------------------------------------------
extern "C" void kernel_launch(void* const* d_in, const int* in_sizes, int n_in,
                              void* d_out, int out_size, void* d_ws,
                              size_t ws_size, hipStream_t stream) {
  const float* x = (const float*)d_in[0];
  const float* W = (const float*)d_in[1];
  const float* b = (const float*)d_in[2];
  const float* trans = (const float*)d_in[3];
  const float* start_t = (const float*)d_in[4];
  const float* end_t = (const float*)d_in[5];
  const int* nwords = (const int*)d_in[6];
  float* out = (float*)d_out;
  float* tags_out = out;            // (B, S) floats
  float* feats_out = out + NROWS;   // (B, S, T) floats

  const size_t plane = (size_t)NROWS * TDIM * sizeof(float);  // 2.23 MB
  float* part = (float*)d_ws;
  const int feats_elems = NROWS * TDIM;
  const int rb = (feats_elems + 255) / 256;

  if (ws_size >= 8 * plane) {
    gemm_partial<8><<<NROWS / 64, 512, 0, stream>>>(x, W, part);
    reduce_bias<8><<<rb, 256, 0, stream>>>(part, b, feats_out);
  } else if (ws_size >= 4 * plane) {
    gemm_partial<4><<<NROWS / 64, 256, 0, stream>>>(x, W, part);
    reduce_bias<4><<<rb, 256, 0, stream>>>(part, b, feats_out);
  } else {
    gemm_partial<1><<<NROWS / 64, 64, 0, stream>>>(x, W, feats_out);
    reduce_bias<1><<<rb, 256, 0, stream>>>(feats_out, b, feats_out);
  }
  viterbi_kernel<<<BDIM, 64, 0, stream>>>(feats_out, trans, start_t, end_t,
                                          nwords, tags_out);
}